// Round 1
// baseline (2169.665 us; speedup 1.0000x reference)
//
#include <hip/hip_runtime.h>

// ---------------------------------------------------------------------------
// Adaptive softmax (TransformerXL style), MI355X/gfx950.
// R=512 rows, buckets: n={20000,20000,160000,67735}, d={1024,256,64,16}.
// Pipeline: h->bf16 | Y_i = h P_i^T (MFMA) | cluster logits | logits GEMM
// (MFMA, writes raw logits + per-block softmax partials) | partial reduce |
// normalize | loss gather.
// ---------------------------------------------------------------------------

typedef __bf16 bf16x8 __attribute__((ext_vector_type(8)));
typedef float  f32x4  __attribute__((ext_vector_type(4)));

#define NEG_HUGE (-3.402823466e38f)

__device__ __forceinline__ unsigned short f2bf(float x) {
  unsigned int u = __float_as_uint(x);
  u = (u + 0x7fffu + ((u >> 16) & 1u)) >> 16;   // RNE
  return (unsigned short)u;
}
__device__ __forceinline__ float bf2f(unsigned short h) {
  return __uint_as_float(((unsigned int)h) << 16);
}
// merge two (max, sumexp) pairs; NEG_HUGE sentinel keeps this NaN-free
__device__ __forceinline__ void mergeMS(float& m, float& s, float mo, float so) {
  float mn = fmaxf(m, mo);
  s = s * expf(m - mn) + so * expf(mo - mn);
  m = mn;
}

// ---------------------------------------------------------------- h -> bf16
__global__ __launch_bounds__(256) void convert_h_kernel(
    const float* __restrict__ h, unsigned short* __restrict__ o) {
  int i = (blockIdx.x * 256 + threadIdx.x) * 4;          // 512 blocks, exact
  float4 v = *reinterpret_cast<const float4*>(h + i);
  uint2 u;
  u.x = (unsigned int)f2bf(v.x) | ((unsigned int)f2bf(v.y) << 16);
  u.y = (unsigned int)f2bf(v.z) | ((unsigned int)f2bf(v.w) << 16);
  *reinterpret_cast<uint2*>(o + i) = u;
}

// ---------------------------------------------------------------- GEMM
// C[512, N] = A_bf16[512, K] * B_f32[N, K]^T (+bias)
// SOFTMAX=true : store fp32 raw logits to outF (ld=ldo) + per-block (m,s)
// SOFTMAX=false: store bf16 to outH (ld=ldh)
constexpr int GBM = 64, GBN = 256, GBK = 64, GPK = GBK + 8;

template <bool SOFTMAX>
__global__ __launch_bounds__(256) void gemm_bt_kernel(
    const unsigned short* __restrict__ A, int lda, int K,
    const float* __restrict__ B, const float* __restrict__ bias, int N,
    float* __restrict__ outF, long long ldo,
    unsigned short* __restrict__ outH, int ldh,
    float* __restrict__ partials, int nChunks) {
  __shared__ unsigned short As[GBM][GPK];   // +8 pad keeps b128 align, spreads banks
  __shared__ unsigned short Bs[GBN][GPK];
  __shared__ float red[GBM][4][2];

  const int tid = threadIdx.x;
  const int lane = tid & 63, w = tid >> 6;
  const int q = lane >> 4, l15 = lane & 15;
  const int row0 = blockIdx.x * GBM;
  const int colBase = blockIdx.y * GBN;

  f32x4 acc[4][4];
#pragma unroll
  for (int i = 0; i < 4; ++i)
#pragma unroll
    for (int j = 0; j < 4; ++j) acc[i][j] = (f32x4){0.f, 0.f, 0.f, 0.f};

  for (int k0 = 0; k0 < K; k0 += GBK) {
    __syncthreads();
    // stage A: 64 rows x 64 k bf16 (16B per thread-iter, 2 iters)
#pragma unroll
    for (int i = 0; i < 2; ++i) {
      int f = i * 2048 + tid * 8;
      int r = f >> 6, kk = f & 63;
      uint4 va = make_uint4(0u, 0u, 0u, 0u);
      if (k0 + kk < K)
        va = *reinterpret_cast<const uint4*>(A + (size_t)(row0 + r) * lda + k0 + kk);
      *reinterpret_cast<uint4*>(&As[r][kk]) = va;
    }
    // stage B: 256 cols x 64 k, fp32 global -> bf16 LDS
#pragma unroll
    for (int i = 0; i < 16; ++i) {
      int f = i * 1024 + tid * 4;
      int c = f >> 6, kk = f & 63;
      int col = colBase + c;
      float4 v = make_float4(0.f, 0.f, 0.f, 0.f);
      if (col < N && k0 + kk < K)
        v = *reinterpret_cast<const float4*>(B + (size_t)col * K + k0 + kk);
      uint2 u;
      u.x = (unsigned int)f2bf(v.x) | ((unsigned int)f2bf(v.y) << 16);
      u.y = (unsigned int)f2bf(v.z) | ((unsigned int)f2bf(v.w) << 16);
      *reinterpret_cast<uint2*>(&Bs[c][kk]) = u;
    }
    __syncthreads();
#pragma unroll
    for (int ks = 0; ks < GBK; ks += 32) {
      bf16x8 fa[4], fb[4];
#pragma unroll
      for (int mb = 0; mb < 4; ++mb)
        fa[mb] = *reinterpret_cast<const bf16x8*>(&As[mb * 16 + l15][ks + q * 8]);
#pragma unroll
      for (int nb = 0; nb < 4; ++nb)
        fb[nb] = *reinterpret_cast<const bf16x8*>(&Bs[w * 64 + nb * 16 + l15][ks + q * 8]);
#pragma unroll
      for (int mb = 0; mb < 4; ++mb)
#pragma unroll
        for (int nb = 0; nb < 4; ++nb)
          acc[mb][nb] = __builtin_amdgcn_mfma_f32_16x16x32_bf16(
              fa[mb], fb[nb], acc[mb][nb], 0, 0, 0);
    }
  }

  int colg[4];
#pragma unroll
  for (int nb = 0; nb < 4; ++nb) colg[nb] = colBase + w * 64 + nb * 16 + l15;

  if (SOFTMAX) {
    float bv[4];
#pragma unroll
    for (int nb = 0; nb < 4; ++nb) bv[nb] = (colg[nb] < N) ? bias[colg[nb]] : 0.f;
#pragma unroll
    for (int mb = 0; mb < 4; ++mb)
#pragma unroll
      for (int nb = 0; nb < 4; ++nb)
#pragma unroll
        for (int r = 0; r < 4; ++r) acc[mb][nb][r] += bv[nb];
    // raw logits -> d_out (normalized later)
#pragma unroll
    for (int mb = 0; mb < 4; ++mb)
#pragma unroll
      for (int nb = 0; nb < 4; ++nb)
        if (colg[nb] < N) {
#pragma unroll
          for (int r = 0; r < 4; ++r) {
            int rowg = row0 + mb * 16 + q * 4 + r;
            outF[(size_t)rowg * ldo + colg[nb]] = acc[mb][nb][r];
          }
        }
    // per-row (m, sumexp) over this block's 256 cols
#pragma unroll
    for (int mb = 0; mb < 4; ++mb) {
#pragma unroll
      for (int r = 0; r < 4; ++r) {
        float mx = NEG_HUGE, s = 0.f;
#pragma unroll
        for (int nb = 0; nb < 4; ++nb)
          if (colg[nb] < N) mx = fmaxf(mx, acc[mb][nb][r]);
#pragma unroll
        for (int nb = 0; nb < 4; ++nb)
          if (colg[nb] < N) s += expf(acc[mb][nb][r] - mx);
        for (int off = 1; off < 16; off <<= 1) {   // reduce over quad's 16 lanes
          float mo = __shfl_xor(mx, off);
          float so = __shfl_xor(s, off);
          mergeMS(mx, s, mo, so);
        }
        if (l15 == 0) {
          red[mb * 16 + q * 4 + r][w][0] = mx;
          red[mb * 16 + q * 4 + r][w][1] = s;
        }
      }
    }
    __syncthreads();
    if (tid < 64) {
      float m = red[tid][0][0], s = red[tid][0][1];
#pragma unroll
      for (int ww = 1; ww < 4; ++ww) mergeMS(m, s, red[tid][ww][0], red[tid][ww][1]);
      size_t pi = ((size_t)(row0 + tid) * nChunks + blockIdx.y) * 2;
      partials[pi] = m;
      partials[pi + 1] = s;
    }
  } else {
#pragma unroll
    for (int mb = 0; mb < 4; ++mb)
#pragma unroll
      for (int nb = 0; nb < 4; ++nb)
        if (colg[nb] < N) {
#pragma unroll
          for (int r = 0; r < 4; ++r) {
            int rowg = row0 + mb * 16 + q * 4 + r;
            outH[(size_t)rowg * ldh + colg[nb]] = f2bf(acc[mb][nb][r]);
          }
        }
  }
}

// ------------------------------------------------- cluster logits [512 x 3]
__global__ __launch_bounds__(192) void cluster_kernel(
    const unsigned short* __restrict__ Y0, const float* __restrict__ CW,
    const float* __restrict__ CB, float* __restrict__ CL) {
  int row = blockIdx.x;
  int w = threadIdx.x >> 6, lane = threadIdx.x & 63;
  float s = 0.f;
  for (int k = lane; k < 1024; k += 64)
    s += bf2f(Y0[row * 1024 + k]) * CW[w * 1024 + k];
  for (int off = 32; off > 0; off >>= 1) s += __shfl_xor(s, off);
  if (lane == 0) CL[row * 3 + w] = s + CB[w];
}

// ------------------------------------- reduce partials -> (m, log sumexp)
__global__ __launch_bounds__(128) void reduce_stats_kernel(
    const float* __restrict__ part, const float* __restrict__ CL,
    float* __restrict__ stats) {
  const int nch[4] = {79, 79, 625, 265};
  const long long poff[4] = {0, 80896, 161792, 801792};  // floats
  int row = blockIdx.x >> 2, b = blockIdx.x & 3;
  const float* p = part + poff[b] + (long long)row * nch[b] * 2;
  float m = NEG_HUGE, s = 0.f;
  for (int j = threadIdx.x; j < nch[b]; j += 128) mergeMS(m, s, p[j * 2], p[j * 2 + 1]);
  for (int off = 1; off < 64; off <<= 1) {
    float mo = __shfl_xor(m, off);
    float so = __shfl_xor(s, off);
    mergeMS(m, s, mo, so);
  }
  __shared__ float sm[2][2];
  int w = threadIdx.x >> 6;
  if ((threadIdx.x & 63) == 0) { sm[w][0] = m; sm[w][1] = s; }
  __syncthreads();
  if (threadIdx.x == 0) {
    mergeMS(m, s, sm[1][0], sm[1][1]);
    if (b == 0)  // head softmax includes the 3 cluster logits
      for (int c = 0; c < 3; ++c) mergeMS(m, s, CL[row * 3 + c], 1.f);
    stats[(row * 4 + b) * 2] = m;
    stats[(row * 4 + b) * 2 + 1] = logf(s);
  }
}

// ------------------------------------------------------------- normalize
__global__ __launch_bounds__(256) void normalize_kernel(
    float* __restrict__ out, const float* __restrict__ stats,
    const float* __restrict__ CL) {
  long long idx = (long long)blockIdx.x * 256 + threadIdx.x;  // exact grid
  int row = (int)(idx / 267735LL);
  int col = (int)(idx - (long long)row * 267735LL);
  int b = (col < 20000) ? 0 : (col < 40000) ? 1 : (col < 200000) ? 2 : 3;
  float m = stats[(row * 4 + b) * 2];
  float L = stats[(row * 4 + b) * 2 + 1];
  float off = 0.f;
  if (b > 0) off = CL[row * 3 + (b - 1)] - stats[row * 8] - stats[row * 8 + 1];
  out[idx] = out[idx] - m - L + off;
}

// ------------------------------------------------------------------ loss
__global__ __launch_bounds__(512) void loss_kernel(
    const float* __restrict__ out, const int* __restrict__ target,
    float* __restrict__ lossOut) {
  __shared__ float sm[512];
  int t = threadIdx.x;
  sm[t] = out[(size_t)t * 267735 + target[t]];  // final lp at target col
  __syncthreads();
  for (int s = 256; s > 0; s >>= 1) {
    if (t < s) sm[t] += sm[t + s];
    __syncthreads();
  }
  if (t == 0) lossOut[0] = -sm[0] / 512.f;
}

// ---------------------------------------------------------------------------
extern "C" void kernel_launch(void* const* d_in, const int* in_sizes, int n_in,
                              void* d_out, int out_size, void* d_ws, size_t ws_size,
                              hipStream_t stream) {
  const float* hidden = (const float*)d_in[0];
  const int* target = (const int*)d_in[1];
  const float* CW = (const float*)d_in[2];
  const float* CB = (const float*)d_in[3];
  const float* W[4] = {(const float*)d_in[4], (const float*)d_in[7],
                       (const float*)d_in[10], (const float*)d_in[13]};
  const float* Bb[4] = {(const float*)d_in[5], (const float*)d_in[8],
                        (const float*)d_in[11], (const float*)d_in[14]};
  const float* P[4] = {(const float*)d_in[6], (const float*)d_in[9],
                       (const float*)d_in[12], (const float*)d_in[15]};

  char* ws = (char*)d_ws;   // ~6.8 MB used
  unsigned short* hbf = (unsigned short*)(ws + 0);
  unsigned short* Y[4] = {(unsigned short*)(ws + 1048576),
                          (unsigned short*)(ws + 2097152),
                          (unsigned short*)(ws + 2359296),
                          (unsigned short*)(ws + 2424832)};
  float* CL = (float*)(ws + 2441216);
  float* stats = (float*)(ws + 2447360);
  float* part = (float*)(ws + 2463744);

  float* out = (float*)d_out;
  const int dims[4] = {1024, 256, 64, 16};
  const int nvoc[4] = {20000, 20000, 160000, 67735};
  const int colOff[4] = {0, 20000, 40000, 200000};
  const int nch[4] = {79, 79, 625, 265};
  const long long poffF[4] = {0, 80896, 161792, 801792};

  convert_h_kernel<<<512, 256, 0, stream>>>(hidden, hbf);
  for (int i = 0; i < 4; ++i) {
    dim3 g(8, (dims[i] + 255) / 256);
    gemm_bt_kernel<false><<<g, 256, 0, stream>>>(hbf, 1024, 1024, P[i], nullptr,
                                                 dims[i], nullptr, 0, Y[i], dims[i],
                                                 nullptr, 0);
  }
  cluster_kernel<<<512, 192, 0, stream>>>(Y[0], CW, CB, CL);
  for (int i = 0; i < 4; ++i) {
    dim3 g(8, nch[i]);   // x = m-tiles (fast-varying) so W tiles hit L2 across m
    gemm_bt_kernel<true><<<g, 256, 0, stream>>>(Y[i], dims[i], dims[i], W[i], Bb[i],
                                                nvoc[i], out + colOff[i], 267735LL,
                                                nullptr, 0, part + poffF[i], nch[i]);
  }
  reduce_stats_kernel<<<512 * 4, 128, 0, stream>>>(part, CL, stats);
  normalize_kernel<<<535470, 256, 0, stream>>>(out, stats, CL);
  loss_kernel<<<1, 512, 0, stream>>>(out, target, out + 137080320LL);
}